// Round 3
// baseline (438.895 us; speedup 1.0000x reference)
//
#include <hip/hip_runtime.h>
#include <math.h>

// Problem constants (from reference)
#define NDIM 64
#define NK   128
#define ALPHA_DP 1.0
#define TAU0 0.0
#define C0v  1.0
#define N0v  ((double)(NDIM + 2))
#define B0v  1.0

// ---------------- device math helpers (double) ----------------
__device__ double digamma_d(double x) {
    double r = 0.0;
    while (x < 6.0) { r -= 1.0 / x; x += 1.0; }
    double inv = 1.0 / x, inv2 = inv * inv;
    double s = log(x) - 0.5 * inv
        - inv2 * (1.0/12.0 - inv2 * (1.0/120.0 - inv2 * (1.0/252.0
            - inv2 * (1.0/240.0 - inv2 * (1.0/132.0)))));
    return s + r;
}

// ---------------- kernel 1: cluster prep (1 block, K threads) ----------------
// ws layout: [0]=ll accumulator (double), [1]=kl total (double),
//            constk (K floats), nbD (D*K floats, d-major), w2D (D*K floats, d-major)
__global__ void prep_kernel(const float* __restrict__ nat_u,
                            const float* __restrict__ nat_v,
                            const float* __restrict__ nat_tau,
                            const float* __restrict__ nat_c,
                            const float* __restrict__ nat_n,
                            const float* __restrict__ nat_B,
                            double* __restrict__ scal,
                            float* __restrict__ constk,
                            float* __restrict__ nbD,
                            float* __restrict__ w2D) {
    const int k = threadIdx.x;          // 0..K-1
    const int D = NDIM, K = NK;

    double u = (double)nat_u[k] + 1.0;
    double v = (double)nat_v[k] + 1.0;
    double c = (double)nat_c[k];
    double n = (double)nat_n[k] - (double)D - 2.0;

    double dg_u  = digamma_d(u);
    double dg_v  = digamma_d(v);
    double dg_uv = digamma_d(u + v);

    const double a0g = 0.5 * N0v;
    const double b0g = 0.5 * B0v;
    double sum_log_halfB = 0.0, sum_t2nb = 0.0, sum_nb = 0.0;
    double kl_g_d = 0.0, kl_n_d = 0.0;

    for (int d = 0; d < D; ++d) {
        double tau = (double)nat_tau[k * D + d] / c;
        double B   = (double)nat_B[k * D + d] - c * tau * tau;
        double nb  = n / B;
        nbD[d * K + k] = (float)nb;                 // d-major for the maha kernel
        w2D[d * K + k] = (float)(-2.0 * tau * nb);
        sum_log_halfB += log(0.5 * B);
        sum_t2nb += tau * tau * nb;
        sum_nb   += nb;
        double b1 = 0.5 * B;
        kl_g_d += a0g * (log(b1) - log(b0g)) + (0.5 * n) * (b0g - b1) / b1;
        kl_n_d += C0v * nb * (tau - TAU0) * (tau - TAU0);
    }

    double a1 = 0.5 * n;
    double e_log_det = (double)D * digamma_d(a1) - sum_log_halfB;

    // stick-breaking exclusive prefix of E[log(1-s)]
    __shared__ double sh[NK];
    sh[k] = dg_v - dg_uv;
    __syncthreads();
    double pre = 0.0;
    for (int j = 0; j < k; ++j) pre += sh[j];
    double e_log_pi = dg_u - dg_uv + pre;

    // const_k folds e_log_pi + 0.5*(e_log_det - D log 2pi - sum tau^2 nb - D/c - sum_nb)
    // (sum_nb folded because main kernel accumulates nb*(x^2-1) for fp32 accuracy)
    const double LOG2PI = 1.8378770664093454836;
    double ck = e_log_pi + 0.5 * (e_log_det - (double)D * LOG2PI
                                  - sum_t2nb - (double)D / c - sum_nb);
    constk[k] = (float)ck;

    // KL terms
    const double a0 = 1.0, b0 = ALPHA_DP;
    double kl_beta = lgamma(u + v) - lgamma(u) - lgamma(v)
        - (lgamma(a0 + b0) - lgamma(a0) - lgamma(b0))
        + (u - a0) * dg_u + (v - b0) * dg_v + (a0 + b0 - u - v) * dg_uv;

    double dga1 = digamma_d(a1);
    double kl_gamma = (double)D * ((a1 - a0g) * dga1 - lgamma(a1) + lgamma(a0g)) + kl_g_d;

    double kl_norm = 0.5 * ((double)D * (log(c / C0v) + C0v / c - 1.0) + kl_n_d);

    __syncthreads();
    sh[k] = kl_beta + kl_gamma + kl_norm;
    __syncthreads();
    if (k == 0) {
        double t = 0.0;
        for (int j = 0; j < K; ++j) t += sh[j];
        scal[1] = t;     // kl total
        scal[0] = 0.0;   // ll accumulator (ws is poisoned every call)
    }
}

// ---------------- kernel 2: wave-split-K broadcast-FMA + fused softmax ----------------
// Block = 4 waves, 128 points. Waves {0,1}: points 0..63, k-halves {0,1}.
// Waves {2,3}: points 64..127, k-halves {0,1}. Coefficient addresses are
// wave-uniform (kbase via readfirstlane) -> SGPR broadcast; acc[64]/thread
// keeps VGPR <=128 (4 waves/SIMD), no AGPR overflow.
#define KH 64
__global__ __launch_bounds__(256, 4) void maha_kernel(
    const float* __restrict__ x,
    const float* __restrict__ constk,
    const float* __restrict__ nbD,     // [d][k]
    const float* __restrict__ w2D,     // [d][k]
    float* __restrict__ r,
    double* __restrict__ scal) {
    const int K = NK, D = NDIM;
    const int tid  = threadIdx.x;
    const int lane = tid & 63;
    const int wid  = __builtin_amdgcn_readfirstlane(tid >> 6);   // 0..3, scalar
    const int kb   = (wid & 1) * KH;                             // scalar k-base
    const long n   = (long)blockIdx.x * 128 + (wid >> 1) * 64 + lane;
    const float* __restrict__ xp = x + n * D;

    float acc[KH];
#pragma unroll
    for (int k = 0; k < KH; ++k) acc[k] = 0.f;

    float4 xv = *(const float4*)(xp);            // prefetched current chunk
    for (int dc = 0; dc < D / 4; ++dc) {
        float4 xn;
        if (dc < D / 4 - 1) xn = *(const float4*)(xp + 4 * dc + 4);  // prefetch next
        float xs4[4] = {xv.x, xv.y, xv.z, xv.w};
#pragma unroll
        for (int j = 0; j < 4; ++j) {
            const int d = dc * 4 + j;
            const float xd = xs4[j];
            const float yd = fmaf(xd, xd, -1.0f);        // centered x^2 (accuracy)
            const float* __restrict__ cw = w2D + d * K + kb;  // wave-uniform
            const float* __restrict__ cn = nbD + d * K + kb;
#pragma unroll
            for (int k = 0; k < KH; ++k) {
                float t = fmaf(cw[k], xd, acc[k]);       // v_fmac vacc, s_w2, v_x
                acc[k] = fmaf(cn[k], yd, t);             // v_fmac vacc, s_nb, v_y
            }
        }
        xv = xn;
    }

    // local logits for this k-half: l[k] = constk[kb+k] - 0.5*acc[k]
    const float* __restrict__ ckp = constk + kb;         // wave-uniform
    float m = -3.4e38f;
#pragma unroll
    for (int k = 0; k < KH; ++k) {
        acc[k] = fmaf(acc[k], -0.5f, ckp[k]);
        m = fmaxf(m, acc[k]);
    }
    float s = 0.f;
#pragma unroll
    for (int k = 0; k < KH; ++k) {
        acc[k] = __expf(acc[k] - m);
        s += acc[k];
    }

    // combine the two k-halves (wave pair) through LDS
    __shared__ float sm[4][64];
    __shared__ float ss[4][64];
    sm[wid][lane] = m;
    ss[wid][lane] = s;
    __syncthreads();
    const float m_o = sm[wid ^ 1][lane];
    const float s_o = ss[wid ^ 1][lane];
    const float M = fmaxf(m, m_o);
    const float stot = s * __expf(m - M) + s_o * __expf(m_o - M);
    const float scale = __expf(m - M) / stot;

    float* __restrict__ rp = r + n * K + kb;
#pragma unroll
    for (int q = 0; q < KH / 4; ++q) {
        float4 v = make_float4(acc[4 * q] * scale, acc[4 * q + 1] * scale,
                               acc[4 * q + 2] * scale, acc[4 * q + 3] * scale);
        *(float4*)(rp + 4 * q) = v;
    }

    // ll: log_norm = M + log(stot), counted once per point (k-half-0 waves)
    if ((wid & 1) == 0) {
        double ln = (double)M + log((double)stot);
#pragma unroll
        for (int off = 32; off >= 1; off >>= 1) ln += __shfl_xor(ln, off, 64);
        if (lane == 0) atomicAdd(scal, ln);
    }
}

// ---------------- kernel 3: finalize scalar ----------------
__global__ void finalize_kernel(const double* __restrict__ scal, float* __restrict__ out) {
    out[0] = (float)(scal[1] - scal[0]);   // -elbo = kl_total - ll
}

extern "C" void kernel_launch(void* const* d_in, const int* in_sizes, int n_in,
                              void* d_out, int out_size, void* d_ws, size_t ws_size,
                              hipStream_t stream) {
    const float* x       = (const float*)d_in[0];
    const float* nat_u   = (const float*)d_in[1];
    const float* nat_v   = (const float*)d_in[2];
    const float* nat_tau = (const float*)d_in[3];
    const float* nat_c   = (const float*)d_in[4];
    const float* nat_n   = (const float*)d_in[5];
    const float* nat_B   = (const float*)d_in[6];

    const int D = NDIM, K = NK;
    const int N = in_sizes[0] / D;

    float* out = (float*)d_out;

    // ws layout (~66 KB used)
    double* scal  = (double*)d_ws;
    float* constk = (float*)((char*)d_ws + 16);
    float* nbD    = constk + K;               // 528 B offset, 16B-aligned
    float* w2D    = nbD + (size_t)K * D;

    prep_kernel<<<1, K, 0, stream>>>(nat_u, nat_v, nat_tau, nat_c, nat_n, nat_B,
                                     scal, constk, nbD, w2D);
    maha_kernel<<<N / 128, 256, 0, stream>>>(x, constk, nbD, w2D, out, scal);
    finalize_kernel<<<1, 1, 0, stream>>>(scal, out + (size_t)N * K);
}

// Round 4
// 391.860 us; speedup vs baseline: 1.1200x; 1.1200x over previous
//
#include <hip/hip_runtime.h>
#include <math.h>

// Problem constants (from reference)
#define NDIM 64
#define NK   128
#define ALPHA_DP 1.0
#define TAU0 0.0
#define C0v  1.0
#define N0v  ((double)(NDIM + 2))
#define B0v  1.0

typedef __attribute__((ext_vector_type(8))) short bf16x8;
typedef __attribute__((ext_vector_type(16))) float f32x16;

// ---------------- device math helpers ----------------
__device__ double digamma_d(double x) {
    double r = 0.0;
    while (x < 6.0) { r -= 1.0 / x; x += 1.0; }
    double inv = 1.0 / x, inv2 = inv * inv;
    double s = log(x) - 0.5 * inv
        - inv2 * (1.0/12.0 - inv2 * (1.0/120.0 - inv2 * (1.0/252.0
            - inv2 * (1.0/240.0 - inv2 * (1.0/132.0)))));
    return s + r;
}

__device__ inline unsigned pack_bf16_hi(float a, float b) {
    // dword = {bf16(a) in low16, bf16(b) in high16}; truncation split
    return (__float_as_uint(a) >> 16) | (__float_as_uint(b) & 0xffff0000u);
}

// ---------------- kernel 1: cluster prep (1 block, K threads) ----------------
// ws: scal[2] doubles | constk[128] f32 | Wh[128][128] ushort | Wl[128][128] ushort
// W[n][j]: j<64 -> tau*nb (== -0.5*w2), j>=64 -> -0.5*nb.  (-0.5 folded into W)
__global__ void prep_kernel(const float* __restrict__ nat_u,
                            const float* __restrict__ nat_v,
                            const float* __restrict__ nat_tau,
                            const float* __restrict__ nat_c,
                            const float* __restrict__ nat_n,
                            const float* __restrict__ nat_B,
                            double* __restrict__ scal,
                            float* __restrict__ constk,
                            unsigned short* __restrict__ Wh,
                            unsigned short* __restrict__ Wl) {
    const int k = threadIdx.x;          // cluster 0..127
    const int D = NDIM, K = NK;

    double u = (double)nat_u[k] + 1.0;
    double v = (double)nat_v[k] + 1.0;
    double c = (double)nat_c[k];
    double n = (double)nat_n[k] - (double)D - 2.0;

    double dg_u  = digamma_d(u);
    double dg_v  = digamma_d(v);
    double dg_uv = digamma_d(u + v);

    const double a0g = 0.5 * N0v;
    const double b0g = 0.5 * B0v;
    double sum_log_halfB = 0.0, sum_t2nb = 0.0, sum_nb = 0.0;
    double kl_g_d = 0.0, kl_n_d = 0.0;

    for (int d = 0; d < D; ++d) {
        double tau = (double)nat_tau[k * D + d] / c;
        double B   = (double)nat_B[k * D + d] - c * tau * tau;
        double nb  = n / B;
        // W row for this cluster, split into bf16 hi/lo
        float wx = (float)(tau * nb);          // coefficient on x_d
        float wy = (float)(-0.5 * nb);         // coefficient on y_d = x_d^2 - 1
        unsigned bx = __float_as_uint(wx), by = __float_as_uint(wy);
        float hx = __uint_as_float(bx & 0xffff0000u);
        float hy = __uint_as_float(by & 0xffff0000u);
        Wh[k * 128 + d]      = (unsigned short)(bx >> 16);
        Wh[k * 128 + 64 + d] = (unsigned short)(by >> 16);
        Wl[k * 128 + d]      = (unsigned short)(__float_as_uint(wx - hx) >> 16);
        Wl[k * 128 + 64 + d] = (unsigned short)(__float_as_uint(wy - hy) >> 16);

        sum_log_halfB += log(0.5 * B);
        sum_t2nb += tau * tau * nb;
        sum_nb   += nb;
        double b1 = 0.5 * B;
        kl_g_d += a0g * (log(b1) - log(b0g)) + (0.5 * n) * (b0g - b1) / b1;
        kl_n_d += C0v * nb * (tau - TAU0) * (tau - TAU0);
    }

    double a1 = 0.5 * n;
    double e_log_det = (double)D * digamma_d(a1) - sum_log_halfB;

    __shared__ double sh[NK];
    sh[k] = dg_v - dg_uv;
    __syncthreads();
    double pre = 0.0;
    for (int j = 0; j < k; ++j) pre += sh[j];
    double e_log_pi = dg_u - dg_uv + pre;

    // logit = MFMA_acc + constk ; MFMA_acc = -0.5*(sum w2 x + sum nb (x^2-1))
    const double LOG2PI = 1.8378770664093454836;
    double ck = e_log_pi + 0.5 * (e_log_det - (double)D * LOG2PI
                                  - sum_t2nb - (double)D / c - sum_nb);
    constk[k] = (float)ck;

    const double a0 = 1.0, b0 = ALPHA_DP;
    double kl_beta = lgamma(u + v) - lgamma(u) - lgamma(v)
        - (lgamma(a0 + b0) - lgamma(a0) - lgamma(b0))
        + (u - a0) * dg_u + (v - b0) * dg_v + (a0 + b0 - u - v) * dg_uv;

    double dga1 = digamma_d(a1);
    double kl_gamma = (double)D * ((a1 - a0g) * dga1 - lgamma(a1) + lgamma(a0g)) + kl_g_d;
    double kl_norm = 0.5 * ((double)D * (log(c / C0v) + C0v / c - 1.0) + kl_n_d);

    __syncthreads();
    sh[k] = kl_beta + kl_gamma + kl_norm;
    __syncthreads();
    if (k == 0) {
        double t = 0.0;
        for (int j = 0; j < K; ++j) t += sh[j];
        scal[1] = t;
        scal[0] = 0.0;
    }
}

// ---------------- kernel 2: MFMA maha + fused softmax ----------------
// Block = 4 waves. Per iteration: 64 points. Wave w owns cluster strip w*32..+31,
// computes two 32x32 C-tiles (points 0..31, 32..63) with split-bf16 (hh+lh+hl).
// A (x | x^2-1, hi/lo bf16) staged in LDS, XOR-swizzled 16B chunks.
// Epilogue: logits -> LDS [64][132], scan threads do softmax + coalesced stores.
#define ITERS 2

// LDS map (bytes): Ah [0,16384) rows 64x256B ; Al [16384,32768)
//   union: logits f32 [64][132] = 33792 B ; lnarr f32[64] at 33792
__global__ __launch_bounds__(256, 3) void maha_kernel(
    const float* __restrict__ x,
    const float* __restrict__ constk,
    const unsigned short* __restrict__ Wh,
    const unsigned short* __restrict__ Wl,
    float* __restrict__ r,
    double* __restrict__ scal) {
    __shared__ __align__(16) unsigned char smem[34304];
    unsigned char* Ah = smem;
    unsigned char* Al = smem + 16384;
    float* lg    = (float*)smem;            // row stride 132 floats
    float* lnarr = (float*)(smem + 33792);

    const int tid  = threadIdx.x;
    const int lane = tid & 63;
    const int w    = tid >> 6;              // wave id = cluster strip
    const int g    = lane >> 5;             // k-group (0/1)
    const int m0   = lane & 31;
    const int ncol = (w << 5) + m0;         // this lane's cluster column

    // ---- load B fragments once (ws table, L2-hot) ----
    bf16x8 Bh[8], Bl[8];
    {
        const unsigned short* bh = Wh + ncol * 128 + g * 8;
        const unsigned short* bl = Wl + ncol * 128 + g * 8;
#pragma unroll
        for (int kc = 0; kc < 8; ++kc) {
            Bh[kc] = *(const bf16x8*)(bh + kc * 16);
            Bl[kc] = *(const bf16x8*)(bl + kc * 16);
        }
    }
    const float ckl = constk[ncol];

    for (int it = 0; it < ITERS; ++it) {
        const long n0 = ((long)blockIdx.x * ITERS + it) * 64;
        __syncthreads();                    // LDS reuse vs previous scan

        // ---- stage A: thread = (point m, j-half) ----
        {
            const int m    = tid & 63;
            const int half = tid >> 6;          // 0..3 -> j in [half*32, half*32+32)
            const int isY  = half >> 1;
            const int d0   = (half & 1) * 32;
            const float* xr = x + (n0 + m) * NDIM + d0;
            float f[32];
#pragma unroll
            for (int i = 0; i < 8; ++i)
                *(float4*)(f + 4 * i) = *(const float4*)(xr + 4 * i);
            if (isY) {
#pragma unroll
                for (int i = 0; i < 32; ++i) f[i] = fmaf(f[i], f[i], -1.0f);
            }
            unsigned char* ahr = Ah + m * 256;
            unsigned char* alr = Al + m * 256;
#pragma unroll
            for (int q = 0; q < 4; ++q) {
                const int c  = half * 4 + q;            // 16B chunk index 0..15
                const int cs = (c ^ (m & 7)) * 16;      // XOR swizzle
                float* fe = f + q * 8;
                float h[8], l[8];
#pragma unroll
                for (int e = 0; e < 8; ++e) {
                    h[e] = __uint_as_float(__float_as_uint(fe[e]) & 0xffff0000u);
                    l[e] = fe[e] - h[e];
                }
                uint4 uh = make_uint4(pack_bf16_hi(fe[0], fe[1]), pack_bf16_hi(fe[2], fe[3]),
                                      pack_bf16_hi(fe[4], fe[5]), pack_bf16_hi(fe[6], fe[7]));
                uint4 ul = make_uint4(pack_bf16_hi(l[0], l[1]), pack_bf16_hi(l[2], l[3]),
                                      pack_bf16_hi(l[4], l[5]), pack_bf16_hi(l[6], l[7]));
                *(uint4*)(ahr + cs) = uh;
                *(uint4*)(alr + cs) = ul;
            }
        }
        __syncthreads();

        // ---- MFMA K-loop: 8 chunks x (hh, lh, hl) x 2 point-tiles ----
        f32x16 acc0, acc1;
#pragma unroll
        for (int i = 0; i < 16; ++i) { acc0[i] = 0.f; acc1[i] = 0.f; }
#pragma unroll
        for (int kc = 0; kc < 8; ++kc) {
            const int c   = kc * 2 + g;
            const int cs  = (c ^ (m0 & 7)) * 16;
            bf16x8 a0h = *(const bf16x8*)(Ah + m0 * 256 + cs);
            bf16x8 a0l = *(const bf16x8*)(Al + m0 * 256 + cs);
            bf16x8 a1h = *(const bf16x8*)(Ah + (m0 + 32) * 256 + cs);
            bf16x8 a1l = *(const bf16x8*)(Al + (m0 + 32) * 256 + cs);
            acc0 = __builtin_amdgcn_mfma_f32_32x32x16_bf16(a0h, Bh[kc], acc0, 0, 0, 0);
            acc1 = __builtin_amdgcn_mfma_f32_32x32x16_bf16(a1h, Bh[kc], acc1, 0, 0, 0);
            acc0 = __builtin_amdgcn_mfma_f32_32x32x16_bf16(a0l, Bh[kc], acc0, 0, 0, 0);
            acc1 = __builtin_amdgcn_mfma_f32_32x32x16_bf16(a1l, Bh[kc], acc1, 0, 0, 0);
            acc0 = __builtin_amdgcn_mfma_f32_32x32x16_bf16(a0h, Bl[kc], acc0, 0, 0, 0);
            acc1 = __builtin_amdgcn_mfma_f32_32x32x16_bf16(a1h, Bl[kc], acc1, 0, 0, 0);
        }
        __syncthreads();                    // all waves done reading A

        // ---- write logits to LDS: C/D layout col=lane&31, row=(r&3)+8(r>>2)+4(lane>>5)
#pragma unroll
        for (int rg = 0; rg < 16; ++rg) {
            const int p = (rg & 3) + 8 * (rg >> 2) + 4 * g;
            lg[p * 132 + ncol]        = acc0[rg] + ckl;
            lg[(p + 32) * 132 + ncol] = acc1[rg] + ckl;
        }
        __syncthreads();

        // ---- scan: 4 threads per point, softmax + coalesced store ----
        {
            const int p = tid >> 2, q = tid & 3;
            float v[32];
#pragma unroll
            for (int i = 0; i < 8; ++i)
                *(float4*)(v + 4 * i) = *(const float4*)(lg + p * 132 + q * 32 + 4 * i);
            float mx = v[0];
#pragma unroll
            for (int i = 1; i < 32; ++i) mx = fmaxf(mx, v[i]);
            mx = fmaxf(mx, __shfl_xor(mx, 1, 64));
            mx = fmaxf(mx, __shfl_xor(mx, 2, 64));
            float s = 0.f;
#pragma unroll
            for (int i = 0; i < 32; ++i) { v[i] = __expf(v[i] - mx); s += v[i]; }
            s += __shfl_xor(s, 1, 64);
            s += __shfl_xor(s, 2, 64);
            const float inv = 1.0f / s;
            float* rp = r + (n0 + p) * (long)NK + q * 32;
#pragma unroll
            for (int i = 0; i < 8; ++i) {
                float4 o = make_float4(v[4*i] * inv, v[4*i+1] * inv,
                                       v[4*i+2] * inv, v[4*i+3] * inv);
                *(float4*)(rp + 4 * i) = o;
            }
            if (q == 0) lnarr[p] = mx + logf(s);
        }
        __syncthreads();
        if (tid == 0) {
            double t = 0.0;
#pragma unroll 4
            for (int i = 0; i < 64; ++i) t += (double)lnarr[i];
            atomicAdd(scal, t);
        }
    }
}

// ---------------- kernel 3: finalize scalar ----------------
__global__ void finalize_kernel(const double* __restrict__ scal, float* __restrict__ out) {
    out[0] = (float)(scal[1] - scal[0]);   // -elbo = kl_total - ll
}

extern "C" void kernel_launch(void* const* d_in, const int* in_sizes, int n_in,
                              void* d_out, int out_size, void* d_ws, size_t ws_size,
                              hipStream_t stream) {
    const float* x       = (const float*)d_in[0];
    const float* nat_u   = (const float*)d_in[1];
    const float* nat_v   = (const float*)d_in[2];
    const float* nat_tau = (const float*)d_in[3];
    const float* nat_c   = (const float*)d_in[4];
    const float* nat_n   = (const float*)d_in[5];
    const float* nat_B   = (const float*)d_in[6];

    const int N = in_sizes[0] / NDIM;
    float* out = (float*)d_out;

    // ws layout: scal (16B) | constk (512B) | Wh (32 KB) | Wl (32 KB)
    double* scal          = (double*)d_ws;
    float* constk         = (float*)((char*)d_ws + 16);
    unsigned short* Wh    = (unsigned short*)((char*)d_ws + 528);
    unsigned short* Wl    = (unsigned short*)((char*)d_ws + 528 + 32768);

    prep_kernel<<<1, NK, 0, stream>>>(nat_u, nat_v, nat_tau, nat_c, nat_n, nat_B,
                                      scal, constk, Wh, Wl);
    maha_kernel<<<N / (64 * ITERS), 256, 0, stream>>>(x, constk, Wh, Wl, out, scal);
    finalize_kernel<<<1, 1, 0, stream>>>(scal, out + (size_t)N * NK);
}

// Round 5
// 316.234 us; speedup vs baseline: 1.3879x; 1.2391x over previous
//
#include <hip/hip_runtime.h>
#include <math.h>

// Problem constants (from reference)
#define NDIM 64
#define NK   128
#define ALPHA_DP 1.0
#define TAU0 0.0
#define C0v  1.0
#define N0v  ((double)(NDIM + 2))
#define B0v  1.0

#define ITERS 4          // 128-point iterations per block
#define NSLOT 64         // ll partial-sum slots

typedef __attribute__((ext_vector_type(8))) short bf16x8;
typedef __attribute__((ext_vector_type(16))) float f32x16;

// ---------------- device math helpers ----------------
__device__ double digamma_d(double x) {
    double r = 0.0;
    while (x < 6.0) { r -= 1.0 / x; x += 1.0; }
    double inv = 1.0 / x, inv2 = inv * inv;
    double s = log(x) - 0.5 * inv
        - inv2 * (1.0/12.0 - inv2 * (1.0/120.0 - inv2 * (1.0/252.0
            - inv2 * (1.0/240.0 - inv2 * (1.0/132.0)))));
    return s + r;
}

__device__ inline unsigned pack_bf16_hi(float a, float b) {
    // dword = {bf16(a) lo16, bf16(b) hi16}; truncation split
    return (__float_as_uint(a) >> 16) | (__float_as_uint(b) & 0xffff0000u);
}

// fragment-major ushort index for W tables:
// feature f (0..127: x dims then y dims), cluster k.
// layout: [s=k>>5][kc=f>>4][g=(f>>3)&1][n=k&31][j=f&7]
__device__ inline int widx(int f, int k) {
    int kc = f >> 4, g = (f >> 3) & 1, j = f & 7, s = k >> 5, n = k & 31;
    return ((s * 8 + kc) * 2 + g) * 256 + n * 8 + j;
}

// ---------------- kernel 1: cluster prep (1 block, 128 threads) ----------------
// ws: scal[2] dbl | slots[64] dbl | constk[128] f32 | WhL (32KB) | WlL (32KB)
__global__ void prep_kernel(const float* __restrict__ nat_u,
                            const float* __restrict__ nat_v,
                            const float* __restrict__ nat_tau,
                            const float* __restrict__ nat_c,
                            const float* __restrict__ nat_n,
                            const float* __restrict__ nat_B,
                            double* __restrict__ scal,
                            double* __restrict__ slots,
                            float* __restrict__ constk,
                            unsigned short* __restrict__ Wh,
                            unsigned short* __restrict__ Wl) {
    const int k = threadIdx.x;          // cluster 0..127
    const int D = NDIM, K = NK;
    if (k < NSLOT) slots[k] = 0.0;      // zero ll partials (ws is poisoned)

    double u = (double)nat_u[k] + 1.0;
    double v = (double)nat_v[k] + 1.0;
    double c = (double)nat_c[k];
    double n = (double)nat_n[k] - (double)D - 2.0;

    double dg_u  = digamma_d(u);
    double dg_v  = digamma_d(v);
    double dg_uv = digamma_d(u + v);

    const double a0g = 0.5 * N0v;
    const double b0g = 0.5 * B0v;
    double sum_log_halfB = 0.0, sum_t2nb = 0.0, sum_nb = 0.0;
    double kl_g_d = 0.0, kl_n_d = 0.0;

    for (int d = 0; d < D; ++d) {
        double tau = (double)nat_tau[k * D + d] / c;
        double B   = (double)nat_B[k * D + d] - c * tau * tau;
        double nb  = n / B;
        float wx = (float)(tau * nb);          // coefficient on x_d   (feature d)
        float wy = (float)(-0.5 * nb);         // coefficient on y_d=x_d^2-1 (feature 64+d)
        unsigned bx = __float_as_uint(wx), by = __float_as_uint(wy);
        float hx = __uint_as_float(bx & 0xffff0000u);
        float hy = __uint_as_float(by & 0xffff0000u);
        Wh[widx(d, k)]      = (unsigned short)(bx >> 16);
        Wh[widx(64 + d, k)] = (unsigned short)(by >> 16);
        Wl[widx(d, k)]      = (unsigned short)(__float_as_uint(wx - hx) >> 16);
        Wl[widx(64 + d, k)] = (unsigned short)(__float_as_uint(wy - hy) >> 16);

        sum_log_halfB += log(0.5 * B);
        sum_t2nb += tau * tau * nb;
        sum_nb   += nb;
        double b1 = 0.5 * B;
        kl_g_d += a0g * (log(b1) - log(b0g)) + (0.5 * n) * (b0g - b1) / b1;
        kl_n_d += C0v * nb * (tau - TAU0) * (tau - TAU0);
    }

    double a1 = 0.5 * n;
    double e_log_det = (double)D * digamma_d(a1) - sum_log_halfB;

    __shared__ double sh[NK];
    sh[k] = dg_v - dg_uv;
    __syncthreads();
    double pre = 0.0;
    for (int j = 0; j < k; ++j) pre += sh[j];
    double e_log_pi = dg_u - dg_uv + pre;

    // logit = MFMA_acc + constk ; MFMA_acc = sum wx*x + sum wy*(x^2-1)
    const double LOG2PI = 1.8378770664093454836;
    double ck = e_log_pi + 0.5 * (e_log_det - (double)D * LOG2PI
                                  - sum_t2nb - (double)D / c - sum_nb);
    constk[k] = (float)ck;

    const double a0 = 1.0, b0 = ALPHA_DP;
    double kl_beta = lgamma(u + v) - lgamma(u) - lgamma(v)
        - (lgamma(a0 + b0) - lgamma(a0) - lgamma(b0))
        + (u - a0) * dg_u + (v - b0) * dg_v + (a0 + b0 - u - v) * dg_uv;

    double dga1 = digamma_d(a1);
    double kl_gamma = (double)D * ((a1 - a0g) * dga1 - lgamma(a1) + lgamma(a0g)) + kl_g_d;
    double kl_norm = 0.5 * ((double)D * (log(c / C0v) + C0v / c - 1.0) + kl_n_d);

    __syncthreads();
    sh[k] = kl_beta + kl_gamma + kl_norm;
    __syncthreads();
    if (k == 0) {
        double t = 0.0;
        for (int j = 0; j < K; ++j) t += sh[j];
        scal[1] = t;
        scal[0] = 0.0;
    }
}

// ---------------- kernel 2: barrier-free MFMA maha + in-wave softmax ----------------
// Block = 4 waves; each wave independently handles 32 points x all 128 clusters
// (4 strip-tiles of 32x32, split-bf16 hh+lh+hl). W staged once to LDS
// (fragment-major, sequential-sweep reads); A built in registers from global x.
// Softmax entirely in-wave via shfl_xor; C-layout coalesced dword stores.
__global__ __launch_bounds__(256, 2) void maha_kernel(
    const float* __restrict__ x,
    const float* __restrict__ constk,
    const uint4* __restrict__ Wg,      // WhL then WlL, 64 KB fragment-major
    float* __restrict__ r,
    double* __restrict__ slots) {
    __shared__ __align__(16) uint4 W[4096];          // 64 KB
    const int tid = threadIdx.x;
#pragma unroll
    for (int i = 0; i < 16; ++i) W[i * 256 + tid] = Wg[i * 256 + tid];
    __syncthreads();                                  // only barrier in the kernel
    const unsigned short* Wh = (const unsigned short*)W;           // [0,32768)
    const unsigned short* Wl = (const unsigned short*)(W + 2048);  // [32768,65536)

    const int lane = tid & 63;
    const int w    = tid >> 6;
    const int g    = lane >> 5;
    const int m0   = lane & 31;

    float ck[4];
#pragma unroll
    for (int s = 0; s < 4; ++s) ck[s] = constk[s * 32 + m0];

    double dsum = 0.0;

    for (int it = 0; it < ITERS; ++it) {
        const long n0 = (long)blockIdx.x * (128 * ITERS) + it * 128 + w * 32;

        // ---- load this lane's point-row half: dims {g*8+16t .. +8}, t=0..3 ----
        const float* xr = x + (n0 + m0) * NDIM + g * 8;
        float xa[32];
#pragma unroll
        for (int t = 0; t < 4; ++t) {
            *(float4*)(xa + t * 8)     = *(const float4*)(xr + t * 16);
            *(float4*)(xa + t * 8 + 4) = *(const float4*)(xr + t * 16 + 4);
        }

        f32x16 acc[4];
#pragma unroll
        for (int s = 0; s < 4; ++s)
#pragma unroll
            for (int i = 0; i < 16; ++i) acc[s][i] = 0.f;

        // ---- K loop: 8 chunks x 4 strips x (hh, lh, hl) ----
#pragma unroll
        for (int c = 0; c < 8; ++c) {
            float fe[8], lo[8];
#pragma unroll
            for (int e = 0; e < 8; ++e) {
                float xv = xa[((c & 3)) * 8 + e];
                fe[e] = (c < 4) ? xv : fmaf(xv, xv, -1.0f);   // x or y=x^2-1
            }
#pragma unroll
            for (int e = 0; e < 8; ++e) {
                float h = __uint_as_float(__float_as_uint(fe[e]) & 0xffff0000u);
                lo[e] = fe[e] - h;
            }
            union { bf16x8 v; unsigned d[4]; } ah, al;
#pragma unroll
            for (int q = 0; q < 4; ++q) {
                ah.d[q] = pack_bf16_hi(fe[2 * q], fe[2 * q + 1]);
                al.d[q] = pack_bf16_hi(lo[2 * q], lo[2 * q + 1]);
            }
            const int bidx = (c * 2 + g) * 256 + m0 * 8;      // ushort index
#pragma unroll
            for (int s = 0; s < 4; ++s) {
                bf16x8 bh = *(const bf16x8*)(Wh + bidx + s * 4096);
                bf16x8 bl = *(const bf16x8*)(Wl + bidx + s * 4096);
                acc[s] = __builtin_amdgcn_mfma_f32_32x32x16_bf16(ah.v, bh, acc[s], 0, 0, 0);
                acc[s] = __builtin_amdgcn_mfma_f32_32x32x16_bf16(al.v, bh, acc[s], 0, 0, 0);
                acc[s] = __builtin_amdgcn_mfma_f32_32x32x16_bf16(ah.v, bl, acc[s], 0, 0, 0);
            }
        }

        // ---- in-wave softmax per point; C/D: col=lane&31, row=(rg&3)+8*(rg>>2)+4*g ----
#pragma unroll
        for (int rg = 0; rg < 16; ++rg) {
            float l0 = acc[0][rg] + ck[0];
            float l1 = acc[1][rg] + ck[1];
            float l2 = acc[2][rg] + ck[2];
            float l3 = acc[3][rg] + ck[3];
            float M = fmaxf(fmaxf(l0, l1), fmaxf(l2, l3));
            M = fmaxf(M, __shfl_xor(M, 1, 64));
            M = fmaxf(M, __shfl_xor(M, 2, 64));
            M = fmaxf(M, __shfl_xor(M, 4, 64));
            M = fmaxf(M, __shfl_xor(M, 8, 64));
            M = fmaxf(M, __shfl_xor(M, 16, 64));
            float e0 = __expf(l0 - M), e1 = __expf(l1 - M);
            float e2 = __expf(l2 - M), e3 = __expf(l3 - M);
            float S = (e0 + e1) + (e2 + e3);
            S += __shfl_xor(S, 1, 64);
            S += __shfl_xor(S, 2, 64);
            S += __shfl_xor(S, 4, 64);
            S += __shfl_xor(S, 8, 64);
            S += __shfl_xor(S, 16, 64);
            const float inv = __builtin_amdgcn_rcpf(S);
            const int p = (rg & 3) + 8 * (rg >> 2) + 4 * g;
            float* rp = r + (n0 + p) * (long)NK + m0;
            rp[0]  = e0 * inv;
            rp[32] = e1 * inv;
            rp[64] = e2 * inv;
            rp[96] = e3 * inv;
            dsum += (double)(M + __logf(S));   // uniform within 32-lane half
        }
    }

    // ---- ll: combine halves (each half's dsum covers its 16 pts/iter), 1 atomic/wave ----
    double d0  = __shfl(dsum, 0, 64);
    double d32 = __shfl(dsum, 32, 64);
    if (lane == 0) atomicAdd(&slots[(blockIdx.x * 4 + w) & (NSLOT - 1)], d0 + d32);
}

// ---------------- kernel 3: finalize scalar ----------------
__global__ void finalize_kernel(const double* __restrict__ scal,
                                const double* __restrict__ slots,
                                float* __restrict__ out) {
    double ll = 0.0;
    for (int i = 0; i < NSLOT; ++i) ll += slots[i];
    out[0] = (float)(scal[1] - ll);   // -elbo = kl_total - ll
}

extern "C" void kernel_launch(void* const* d_in, const int* in_sizes, int n_in,
                              void* d_out, int out_size, void* d_ws, size_t ws_size,
                              hipStream_t stream) {
    const float* x       = (const float*)d_in[0];
    const float* nat_u   = (const float*)d_in[1];
    const float* nat_v   = (const float*)d_in[2];
    const float* nat_tau = (const float*)d_in[3];
    const float* nat_c   = (const float*)d_in[4];
    const float* nat_n   = (const float*)d_in[5];
    const float* nat_B   = (const float*)d_in[6];

    const int N = in_sizes[0] / NDIM;
    float* out = (float*)d_out;

    // ws layout: scal 16B | slots 512B | constk 512B | W tables 64KB (16B-aligned)
    double* scal       = (double*)d_ws;
    double* slots      = (double*)((char*)d_ws + 16);
    float* constk      = (float*)((char*)d_ws + 16 + 512);
    unsigned short* Wh = (unsigned short*)((char*)d_ws + 1040);
    unsigned short* Wl = (unsigned short*)((char*)d_ws + 1040 + 32768);
    const uint4* Wg    = (const uint4*)((char*)d_ws + 1040);

    prep_kernel<<<1, NK, 0, stream>>>(nat_u, nat_v, nat_tau, nat_c, nat_n, nat_B,
                                      scal, slots, constk, Wh, Wl);
    maha_kernel<<<N / (128 * ITERS), 256, 0, stream>>>(x, constk, Wg, out, slots);
    finalize_kernel<<<1, 1, 0, stream>>>(scal, slots, out + (size_t)N * NK);
}